// Round 12
// baseline (323.988 us; speedup 1.0000x reference)
//
#include <hip/hip_runtime.h>
#include <math.h>

#define N_NODES 50000
#define IN_CH 256
#define HID_CH 128
#define OUT_CH 1000
#define TEXT_DIM 768
#define N_EDGES 800000
#define MAX_DEG 64          // Poisson(16) max over 50k nodes ~ 40; 64 is safe
#define NTVP 12             // tvec partial chunks (768/64)
#define MTILES 782          // ceil(50000/64)
#define NB_FILL 3125        // 800000/256

typedef __attribute__((ext_vector_type(8))) short bf16x8;
typedef __attribute__((ext_vector_type(4))) float f32x4;

union U16B { uint4 u; bf16x8 b; ushort s[8]; };

__device__ inline ushort f2bf(float f) {
    union { float f; unsigned u; } v; v.f = f;
    unsigned u = v.u;
    unsigned r = (u + 0x7FFFu + ((u >> 16) & 1u)) >> 16;  // RNE
    return (ushort)r;
}
__device__ inline float bf2f(unsigned s) {
    union { unsigned u; float f; } v; v.u = s << 16; return v.f;
}

// ---------------------------------------------------------------------------
// transpose tile helper: in fp32 [Kdim][ld_in] -> out bf16 [Npad][Kdim]
// ---------------------------------------------------------------------------
__device__ void transpose_tile(const float* __restrict__ in, int ld_in, int Ndim,
                               int Kdim, ushort* __restrict__ out, int bx, int by) {
    __shared__ float t[64][65];
    int n0 = bx * 64, k0 = by * 64;
    int c = threadIdx.x & 63, r0 = threadIdx.x >> 6;
    for (int r = r0; r < 64; r += 4) {
        int n = n0 + c, k = k0 + r;
        t[r][c] = (n < Ndim) ? in[(size_t)k * ld_in + n] : 0.f;
    }
    __syncthreads();
    for (int r = r0; r < 64; r += 4) {
        out[(size_t)(n0 + r) * Kdim + k0 + c] = f2bf(t[c][r]);
    }
}

// ---------------------------------------------------------------------------
// k_prep (141 blocks): weight transposes, tvec partials, pos zeroing.
// Blocks 0..7: Wt1, 8..11: Wt2, 12..43: Wct, 44..91: tvec_part, 92..140: zero.
// ---------------------------------------------------------------------------
__global__ __launch_bounds__(256)
void k_prep(const float* __restrict__ W1, const float* __restrict__ W2,
            const float* __restrict__ Wc, const float* __restrict__ bc,
            const float* __restrict__ text,
            ushort* __restrict__ Wt1, ushort* __restrict__ Wt2,
            ushort* __restrict__ Wct, float* __restrict__ tvp,
            int4* __restrict__ pos4) {
    int b = blockIdx.x;
    if (b < 8) {                       // Wt1: [256][128] -> [128][256]
        transpose_tile(W1, HID_CH, HID_CH, IN_CH, Wt1, b % 2, b / 2);
    } else if (b < 12) {               // Wt2: [128][128] -> [128][128]
        int j = b - 8;
        transpose_tile(W2, HID_CH, HID_CH, HID_CH, Wt2, j % 2, j / 2);
    } else if (b < 44) {               // Wct: Wc[:128] -> [1024][128]
        int j = b - 12;
        transpose_tile(Wc, OUT_CH, OUT_CH, HID_CH, Wct, j % 16, j / 16);
    } else if (b < 92) {               // tvec partials: 4 o-chunks x 12 t-chunks
        int j = b - 44;
        int o = (j & 3) * 256 + threadIdx.x;
        int p = j >> 2;
        int t0 = p * 64;
        if (o < OUT_CH) {
            float acc = (p == 0) ? bc[o] : 0.f;
#pragma unroll 4
            for (int t = t0; t < t0 + 64; ++t)
                acc += text[t] * Wc[(size_t)(HID_CH + t) * OUT_CH + o];
            tvp[p * OUT_CH + o] = acc;
        }
    } else {                           // zero pos: 49 blocks x 256 int4
        int i = (b - 92) * 256 + threadIdx.x;
        if (i < N_NODES / 4) pos4[i] = make_int4(0, 0, 0, 0);
    }
}

// ---------------------------------------------------------------------------
// Fused layer-1 GEMM + bucket fill (independent work, one dispatch).
// Blocks [0, MTILES): G0 = x @ Wt1^T tile. Blocks [MTILES, MTILES+NB_FILL):
// one edge per thread bucket fill (pos[d] ends as in-degree).
// ---------------------------------------------------------------------------
__global__ __launch_bounds__(256)
void k_gemm1_fill(const float* __restrict__ A, const uint4* __restrict__ Bt,
                  ushort* __restrict__ C,
                  const int* __restrict__ src, const int* __restrict__ dst,
                  int* __restrict__ pos, int* __restrict__ bucket) {
    constexpr int K = IN_CH;           // 256
    constexpr int SLOTS = K / 8;       // 32
    __shared__ uint4 ldsA[64 * SLOTS];
    __shared__ uint4 ldsB[64 * SLOTS];

    if (blockIdx.x >= MTILES) {
        // ---- fill role ----
        int i = (blockIdx.x - MTILES) * 256 + threadIdx.x;
        if (i < N_EDGES) {
            int d = dst[i];
            int slot = atomicAdd(&pos[d], 1);
            if (slot < MAX_DEG) bucket[(d << 6) + slot] = src[i];
        }
        return;
    }

    // ---- GEMM role (fp32 A, K=256, N=128 in 2 chunks) ----
    const int tid = threadIdx.x;
    const int lane = tid & 63;
    const int wid = tid >> 6;
    const int wm = wid >> 1, wn = wid & 1;
    const int mbase = blockIdx.x * 64;
    const int M = N_NODES, N = HID_CH;

    for (int i = tid; i < 64 * SLOTS; i += 256) {
        int row = i / SLOTS, slot = i % SLOTS;
        int grow = mbase + row;
        uint4 val = make_uint4(0u, 0u, 0u, 0u);
        if (grow < M) {
            const float4* Af = (const float4*)A;
            float4 f0 = Af[(size_t)grow * (K / 4) + slot * 2];
            float4 f1 = Af[(size_t)grow * (K / 4) + slot * 2 + 1];
            U16B o;
            o.s[0] = f2bf(f0.x); o.s[1] = f2bf(f0.y);
            o.s[2] = f2bf(f0.z); o.s[3] = f2bf(f0.w);
            o.s[4] = f2bf(f1.x); o.s[5] = f2bf(f1.y);
            o.s[6] = f2bf(f1.z); o.s[7] = f2bf(f1.w);
            val = o.u;
        }
        ldsA[row * SLOTS + (slot ^ (row & 7))] = val;
    }
    __syncthreads();

    bf16x8 afrag[2][K / 32];
#pragma unroll
    for (int mi = 0; mi < 2; ++mi) {
        int row = wm * 32 + mi * 16 + (lane & 15);
#pragma unroll
        for (int ks = 0; ks < K / 32; ++ks) {
            int slot = ks * 4 + (lane >> 4);
            U16B u; u.u = ldsA[row * SLOTS + (slot ^ (row & 7))];
            afrag[mi][ks] = u.b;
        }
    }

#pragma unroll
    for (int chi = 0; chi < 2; ++chi) {
        int nbase = chi * 64;
        __syncthreads();
        for (int i = tid; i < 64 * SLOTS; i += 256) {
            int row = i / SLOTS, slot = i % SLOTS;
            ldsB[row * SLOTS + (slot ^ (row & 7))] = Bt[(size_t)(nbase + row) * SLOTS + slot];
        }
        __syncthreads();

        f32x4 acc[2][2];
#pragma unroll
        for (int mi = 0; mi < 2; ++mi)
#pragma unroll
            for (int ni = 0; ni < 2; ++ni)
                acc[mi][ni] = f32x4{0.f, 0.f, 0.f, 0.f};

#pragma unroll
        for (int ks = 0; ks < K / 32; ++ks) {
            bf16x8 bfr[2];
#pragma unroll
            for (int ni = 0; ni < 2; ++ni) {
                int row = wn * 32 + ni * 16 + (lane & 15);
                int slot = ks * 4 + (lane >> 4);
                U16B u; u.u = ldsB[row * SLOTS + (slot ^ (row & 7))];
                bfr[ni] = u.b;
            }
#pragma unroll
            for (int mi = 0; mi < 2; ++mi)
#pragma unroll
                for (int ni = 0; ni < 2; ++ni)
                    acc[mi][ni] = __builtin_amdgcn_mfma_f32_16x16x32_bf16(
                        afrag[mi][ks], bfr[ni], acc[mi][ni], 0, 0, 0);
        }

#pragma unroll
        for (int ni = 0; ni < 2; ++ni) {
            int col = nbase + wn * 32 + ni * 16 + (lane & 15);
#pragma unroll
            for (int mi = 0; mi < 2; ++mi) {
                int r0 = mbase + wm * 32 + mi * 16 + (lane >> 4) * 4;
#pragma unroll
                for (int j = 0; j < 4; ++j) {
                    int r = r0 + j;
                    if (r < M) C[(size_t)r * N + col] = f2bf(acc[mi][ni][j]);
                }
            }
        }
    }
}

// ---------------------------------------------------------------------------
// MFMA GEMM (layer-2 + classifier): C = A[M,K=128] @ Bt[N,128]^T.
// CLS: fp32 nontemporal out + sum of 12 tvec partials per col; masked edges.
// ---------------------------------------------------------------------------
template<bool CLS, int NCH>
__global__ __launch_bounds__(256)
void k_mfma_gemm(const uint4* __restrict__ Au, const uint4* __restrict__ Bt,
                 void* __restrict__ Cv, const float* __restrict__ tvp,
                 int M, int N) {
    constexpr int K = HID_CH;
    constexpr int SLOTS = K / 8;       // 16
    __shared__ uint4 ldsA[64 * SLOTS];
    __shared__ uint4 ldsB[64 * SLOTS];
    const int tid = threadIdx.x;
    const int lane = tid & 63;
    const int wid = tid >> 6;
    const int wm = wid >> 1, wn = wid & 1;
    const int mbase = blockIdx.x * 64;

    for (int i = tid; i < 64 * SLOTS; i += 256) {
        int row = i / SLOTS, slot = i % SLOTS;
        int grow = mbase + row;
        uint4 val = make_uint4(0u, 0u, 0u, 0u);
        if (grow < M) val = Au[(size_t)grow * SLOTS + slot];
        ldsA[row * SLOTS + (slot ^ (row & 7))] = val;
    }
    __syncthreads();

    bf16x8 afrag[2][K / 32];
#pragma unroll
    for (int mi = 0; mi < 2; ++mi) {
        int row = wm * 32 + mi * 16 + (lane & 15);
#pragma unroll
        for (int ks = 0; ks < K / 32; ++ks) {
            int slot = ks * 4 + (lane >> 4);
            U16B u; u.u = ldsA[row * SLOTS + (slot ^ (row & 7))];
            afrag[mi][ks] = u.b;
        }
    }

#pragma unroll
    for (int chi = 0; chi < NCH; ++chi) {
        int nbase = (blockIdx.y * NCH + chi) * 64;
        __syncthreads();
        for (int i = tid; i < 64 * SLOTS; i += 256) {
            int row = i / SLOTS, slot = i % SLOTS;
            ldsB[row * SLOTS + (slot ^ (row & 7))] = Bt[(size_t)(nbase + row) * SLOTS + slot];
        }
        __syncthreads();

        f32x4 acc[2][2];
#pragma unroll
        for (int mi = 0; mi < 2; ++mi)
#pragma unroll
            for (int ni = 0; ni < 2; ++ni)
                acc[mi][ni] = f32x4{0.f, 0.f, 0.f, 0.f};

#pragma unroll
        for (int ks = 0; ks < K / 32; ++ks) {
            bf16x8 bfr[2];
#pragma unroll
            for (int ni = 0; ni < 2; ++ni) {
                int row = wn * 32 + ni * 16 + (lane & 15);
                int slot = ks * 4 + (lane >> 4);
                U16B u; u.u = ldsB[row * SLOTS + (slot ^ (row & 7))];
                bfr[ni] = u.b;
            }
#pragma unroll
            for (int mi = 0; mi < 2; ++mi)
#pragma unroll
                for (int ni = 0; ni < 2; ++ni)
                    acc[mi][ni] = __builtin_amdgcn_mfma_f32_16x16x32_bf16(
                        afrag[mi][ks], bfr[ni], acc[mi][ni], 0, 0, 0);
        }

#pragma unroll
        for (int ni = 0; ni < 2; ++ni) {
            int col = nbase + wn * 32 + ni * 16 + (lane & 15);
            float tv = 0.f;
            if (CLS && col < N) {
#pragma unroll
                for (int p = 0; p < NTVP; ++p) tv += tvp[p * OUT_CH + col];
            }
#pragma unroll
            for (int mi = 0; mi < 2; ++mi) {
                int r0 = mbase + wm * 32 + mi * 16 + (lane >> 4) * 4;
#pragma unroll
                for (int j = 0; j < 4; ++j) {
                    int r = r0 + j;
                    if (CLS) {
                        if (r < M && col < N)
                            __builtin_nontemporal_store(acc[mi][ni][j] + tv,
                                &((float*)Cv)[(size_t)r * N + col]);
                    } else {
                        if (r < M)
                            ((ushort*)Cv)[(size_t)r * N + col] = f2bf(acc[mi][ni][j]);
                    }
                }
            }
        }
    }
}

// ---------------------------------------------------------------------------
// Aggregate (bf16 H): one wave per node, lane = 2 channels (bf16x2 u32).
// div = rsqrtf(1+deg) on the fly (bit-identical to the dinv-array path).
// ---------------------------------------------------------------------------
template<bool RELU>
__global__ __launch_bounds__(256)
void k_agg(const unsigned* __restrict__ Hu, const int* __restrict__ deg,
           const int* __restrict__ bucket, const float* __restrict__ bias,
           unsigned* __restrict__ Ou) {
    int v = blockIdx.x * 4 + (threadIdx.x >> 6);
    if (v >= N_NODES) return;
    int lane = threadIdx.x & 63;
    int dgv = deg[v];
    float di = rsqrtf(1.0f + (float)dgv);
    unsigned h = Hu[(size_t)v * 64 + lane];
    float a0 = bf2f(h & 0xffffu) * di;
    float a1 = bf2f(h >> 16) * di;
    int dg = dgv > MAX_DEG ? MAX_DEG : dgv;
    const int4* brow = (const int4*)(bucket + (v << 6));
    int j = 0;
    for (; j + 4 <= dg; j += 4) {
        int4 s4 = brow[j >> 2];
        float d0 = rsqrtf(1.0f + (float)deg[s4.x]);
        float d1 = rsqrtf(1.0f + (float)deg[s4.y]);
        float d2 = rsqrtf(1.0f + (float)deg[s4.z]);
        float d3 = rsqrtf(1.0f + (float)deg[s4.w]);
        unsigned q0 = Hu[(size_t)s4.x * 64 + lane];
        unsigned q1 = Hu[(size_t)s4.y * 64 + lane];
        unsigned q2 = Hu[(size_t)s4.z * 64 + lane];
        unsigned q3 = Hu[(size_t)s4.w * 64 + lane];
        a0 += bf2f(q0 & 0xffffu) * d0 + bf2f(q1 & 0xffffu) * d1
            + bf2f(q2 & 0xffffu) * d2 + bf2f(q3 & 0xffffu) * d3;
        a1 += bf2f(q0 >> 16) * d0 + bf2f(q1 >> 16) * d1
            + bf2f(q2 >> 16) * d2 + bf2f(q3 >> 16) * d3;
    }
    for (; j < dg; ++j) {
        int s = bucket[(v << 6) + j];
        float ds = rsqrtf(1.0f + (float)deg[s]);
        unsigned q = Hu[(size_t)s * 64 + lane];
        a0 += bf2f(q & 0xffffu) * ds;
        a1 += bf2f(q >> 16) * ds;
    }
    a0 = a0 * di + bias[lane * 2];
    a1 = a1 * di + bias[lane * 2 + 1];
    if (RELU) { a0 = fmaxf(a0, 0.f); a1 = fmaxf(a1, 0.f); }
    Ou[(size_t)v * 64 + lane] = (unsigned)f2bf(a0) | ((unsigned)f2bf(a1) << 16);
}

// ---------------------------------------------------------------------------
extern "C" void kernel_launch(void* const* d_in, const int* in_sizes, int n_in,
                              void* d_out, int out_size, void* d_ws, size_t ws_size,
                              hipStream_t stream) {
    const float* x    = (const float*)d_in[0];
    const int*   ei   = (const int*)d_in[1];
    const float* text = (const float*)d_in[2];
    const float* W1   = (const float*)d_in[3];
    const float* b1   = (const float*)d_in[4];
    const float* W2   = (const float*)d_in[5];
    const float* b2   = (const float*)d_in[6];
    const float* Wc   = (const float*)d_in[7];
    const float* bc   = (const float*)d_in[8];
    float* out = (float*)d_out;

    const int* e_src = ei;
    const int* e_dst = ei + N_EDGES;

    char* ws = (char*)d_ws;
    size_t off = 0;
    auto alloc = [&](size_t bytes) {
        size_t o = off;
        off += (bytes + 255) & ~(size_t)255;
        return o;
    };
    ushort* G0      = (ushort*)(ws + alloc((size_t)N_NODES * HID_CH * 2));
    ushort* G1      = (ushort*)(ws + alloc((size_t)N_NODES * HID_CH * 2));
    int*    pos     = (int*)   (ws + alloc((size_t)N_NODES * 4));
    int*    bucket  = (int*)   (ws + alloc((size_t)N_NODES * MAX_DEG * 4));
    float*  tvp     = (float*) (ws + alloc((size_t)NTVP * OUT_CH * 4));
    ushort* Wt1     = (ushort*)(ws + alloc((size_t)HID_CH * IN_CH * 2));
    ushort* Wt2     = (ushort*)(ws + alloc((size_t)HID_CH * HID_CH * 2));
    ushort* Wct     = (ushort*)(ws + alloc((size_t)1024 * HID_CH * 2));
    (void)ws_size; (void)in_sizes; (void)n_in; (void)out_size;

    // --- prep: transposes + tvec partials + pos zero (1 dispatch) ---
    k_prep<<<141, 256, 0, stream>>>(W1, W2, Wc, bc, text, Wt1, Wt2, Wct, tvp,
                                    (int4*)pos);

    // --- fused: G0 = x @ W1  ||  bucket fill (1 dispatch) ---
    k_gemm1_fill<<<MTILES + NB_FILL, 256, 0, stream>>>(
        x, (const uint4*)Wt1, G0, e_src, e_dst, pos, bucket);

    // --- agg1: G1 = relu(Agg(G0) + b1) ---
    k_agg<true><<<(N_NODES + 3) / 4, 256, 0, stream>>>(
        (const unsigned*)G0, pos, bucket, b1, (unsigned*)G1);

    // --- layer 2 GEMM: G0 = G1 @ W2 ---
    k_mfma_gemm<false, 1><<<dim3(MTILES, 2), 256, 0, stream>>>(
        (const uint4*)G1, (const uint4*)Wt2, G0, nullptr, N_NODES, HID_CH);

    // --- agg2: G1 = Agg(G0) + b2 ---
    k_agg<false><<<(N_NODES + 3) / 4, 256, 0, stream>>>(
        (const unsigned*)G0, pos, bucket, b2, (unsigned*)G1);

    // --- classifier: out = G1 @ Wct^T + sum(tvp) ; grid (782, 8), NCH=2 ---
    k_mfma_gemm<true, 2><<<dim3(MTILES, 8), 256, 0, stream>>>(
        (const uint4*)G1, (const uint4*)Wct, out, tvp, N_NODES, OUT_CH);
}

// Round 13
// 238.698 us; speedup vs baseline: 1.3573x; 1.3573x over previous
//
#include <hip/hip_runtime.h>
#include <math.h>

#define N_NODES 50000
#define IN_CH 256
#define HID_CH 128
#define OUT_CH 1000
#define TEXT_DIM 768
#define N_EDGES 800000
#define MAX_DEG 64          // Poisson(16) max over 50k nodes ~ 40; 64 is safe
#define NTVP 12             // tvec partial chunks (768/64)
#define MTILES 782          // ceil(50000/64)
#define NB_FILL 3125        // 800000/256

typedef __attribute__((ext_vector_type(8))) short bf16x8;
typedef __attribute__((ext_vector_type(4))) float f32x4;

union U16B { uint4 u; bf16x8 b; ushort s[8]; };

__device__ inline ushort f2bf(float f) {
    union { float f; unsigned u; } v; v.f = f;
    unsigned u = v.u;
    unsigned r = (u + 0x7FFFu + ((u >> 16) & 1u)) >> 16;  // RNE
    return (ushort)r;
}
__device__ inline float bf2f(unsigned s) {
    union { unsigned u; float f; } v; v.u = s << 16; return v.f;
}

// ---------------------------------------------------------------------------
// transpose tile helper: in fp32 [Kdim][ld_in] -> out bf16 [Npad][Kdim]
// ---------------------------------------------------------------------------
__device__ void transpose_tile(const float* __restrict__ in, int ld_in, int Ndim,
                               int Kdim, ushort* __restrict__ out, int bx, int by) {
    __shared__ float t[64][65];
    int n0 = bx * 64, k0 = by * 64;
    int c = threadIdx.x & 63, r0 = threadIdx.x >> 6;
    for (int r = r0; r < 64; r += 4) {
        int n = n0 + c, k = k0 + r;
        t[r][c] = (n < Ndim) ? in[(size_t)k * ld_in + n] : 0.f;
    }
    __syncthreads();
    for (int r = r0; r < 64; r += 4) {
        out[(size_t)(n0 + r) * Kdim + k0 + c] = f2bf(t[c][r]);
    }
}

// ---------------------------------------------------------------------------
// k_prep (141 blocks): weight transposes, tvec partials, pos zeroing.
// Blocks 0..7: Wt1, 8..11: Wt2, 12..43: Wct, 44..91: tvec_part, 92..140: zero.
// ---------------------------------------------------------------------------
__global__ __launch_bounds__(256)
void k_prep(const float* __restrict__ W1, const float* __restrict__ W2,
            const float* __restrict__ Wc, const float* __restrict__ bc,
            const float* __restrict__ text,
            ushort* __restrict__ Wt1, ushort* __restrict__ Wt2,
            ushort* __restrict__ Wct, float* __restrict__ tvp,
            int4* __restrict__ pos4) {
    int b = blockIdx.x;
    if (b < 8) {                       // Wt1: [256][128] -> [128][256]
        transpose_tile(W1, HID_CH, HID_CH, IN_CH, Wt1, b % 2, b / 2);
    } else if (b < 12) {               // Wt2: [128][128] -> [128][128]
        int j = b - 8;
        transpose_tile(W2, HID_CH, HID_CH, HID_CH, Wt2, j % 2, j / 2);
    } else if (b < 44) {               // Wct: Wc[:128] -> [1024][128]
        int j = b - 12;
        transpose_tile(Wc, OUT_CH, OUT_CH, HID_CH, Wct, j % 16, j / 16);
    } else if (b < 92) {               // tvec partials: 4 o-chunks x 12 t-chunks
        int j = b - 44;
        int o = (j & 3) * 256 + threadIdx.x;
        int p = j >> 2;
        int t0 = p * 64;
        if (o < OUT_CH) {
            float acc = (p == 0) ? bc[o] : 0.f;
#pragma unroll 4
            for (int t = t0; t < t0 + 64; ++t)
                acc += text[t] * Wc[(size_t)(HID_CH + t) * OUT_CH + o];
            tvp[p * OUT_CH + o] = acc;
        }
    } else {                           // zero pos: 49 blocks x 256 int4
        int i = (b - 92) * 256 + threadIdx.x;
        if (i < N_NODES / 4) pos4[i] = make_int4(0, 0, 0, 0);
    }
}

// ---------------------------------------------------------------------------
// Fused layer-1 GEMM + bucket fill (independent work, one dispatch).
// Blocks [0, MTILES): G0 = x @ Wt1^T tile. Blocks [MTILES, MTILES+NB_FILL):
// one edge per thread bucket fill (pos[d] ends as in-degree).
// ---------------------------------------------------------------------------
__global__ __launch_bounds__(256)
void k_gemm1_fill(const float* __restrict__ A, const uint4* __restrict__ Bt,
                  ushort* __restrict__ C,
                  const int* __restrict__ src, const int* __restrict__ dst,
                  int* __restrict__ pos, int* __restrict__ bucket) {
    constexpr int K = IN_CH;           // 256
    constexpr int SLOTS = K / 8;       // 32
    __shared__ uint4 ldsA[64 * SLOTS];
    __shared__ uint4 ldsB[64 * SLOTS];

    if (blockIdx.x >= MTILES) {
        // ---- fill role ----
        int i = (blockIdx.x - MTILES) * 256 + threadIdx.x;
        if (i < N_EDGES) {
            int d = dst[i];
            int slot = atomicAdd(&pos[d], 1);
            if (slot < MAX_DEG) bucket[(d << 6) + slot] = src[i];
        }
        return;
    }

    // ---- GEMM role (fp32 A, K=256, N=128 in 2 chunks) ----
    const int tid = threadIdx.x;
    const int lane = tid & 63;
    const int wid = tid >> 6;
    const int wm = wid >> 1, wn = wid & 1;
    const int mbase = blockIdx.x * 64;
    const int M = N_NODES, N = HID_CH;

    for (int i = tid; i < 64 * SLOTS; i += 256) {
        int row = i / SLOTS, slot = i % SLOTS;
        int grow = mbase + row;
        uint4 val = make_uint4(0u, 0u, 0u, 0u);
        if (grow < M) {
            const float4* Af = (const float4*)A;
            float4 f0 = Af[(size_t)grow * (K / 4) + slot * 2];
            float4 f1 = Af[(size_t)grow * (K / 4) + slot * 2 + 1];
            U16B o;
            o.s[0] = f2bf(f0.x); o.s[1] = f2bf(f0.y);
            o.s[2] = f2bf(f0.z); o.s[3] = f2bf(f0.w);
            o.s[4] = f2bf(f1.x); o.s[5] = f2bf(f1.y);
            o.s[6] = f2bf(f1.z); o.s[7] = f2bf(f1.w);
            val = o.u;
        }
        ldsA[row * SLOTS + (slot ^ (row & 7))] = val;
    }
    __syncthreads();

    bf16x8 afrag[2][K / 32];
#pragma unroll
    for (int mi = 0; mi < 2; ++mi) {
        int row = wm * 32 + mi * 16 + (lane & 15);
#pragma unroll
        for (int ks = 0; ks < K / 32; ++ks) {
            int slot = ks * 4 + (lane >> 4);
            U16B u; u.u = ldsA[row * SLOTS + (slot ^ (row & 7))];
            afrag[mi][ks] = u.b;
        }
    }

#pragma unroll
    for (int chi = 0; chi < 2; ++chi) {
        int nbase = chi * 64;
        __syncthreads();
        for (int i = tid; i < 64 * SLOTS; i += 256) {
            int row = i / SLOTS, slot = i % SLOTS;
            ldsB[row * SLOTS + (slot ^ (row & 7))] = Bt[(size_t)(nbase + row) * SLOTS + slot];
        }
        __syncthreads();

        f32x4 acc[2][2];
#pragma unroll
        for (int mi = 0; mi < 2; ++mi)
#pragma unroll
            for (int ni = 0; ni < 2; ++ni)
                acc[mi][ni] = f32x4{0.f, 0.f, 0.f, 0.f};

#pragma unroll
        for (int ks = 0; ks < K / 32; ++ks) {
            bf16x8 bfr[2];
#pragma unroll
            for (int ni = 0; ni < 2; ++ni) {
                int row = wn * 32 + ni * 16 + (lane & 15);
                int slot = ks * 4 + (lane >> 4);
                U16B u; u.u = ldsB[row * SLOTS + (slot ^ (row & 7))];
                bfr[ni] = u.b;
            }
#pragma unroll
            for (int mi = 0; mi < 2; ++mi)
#pragma unroll
                for (int ni = 0; ni < 2; ++ni)
                    acc[mi][ni] = __builtin_amdgcn_mfma_f32_16x16x32_bf16(
                        afrag[mi][ks], bfr[ni], acc[mi][ni], 0, 0, 0);
        }

#pragma unroll
        for (int ni = 0; ni < 2; ++ni) {
            int col = nbase + wn * 32 + ni * 16 + (lane & 15);
#pragma unroll
            for (int mi = 0; mi < 2; ++mi) {
                int r0 = mbase + wm * 32 + mi * 16 + (lane >> 4) * 4;
#pragma unroll
                for (int j = 0; j < 4; ++j) {
                    int r = r0 + j;
                    if (r < M) C[(size_t)r * N + col] = f2bf(acc[mi][ni][j]);
                }
            }
        }
    }
}

// ---------------------------------------------------------------------------
// MFMA GEMM (layer-2 + classifier): C = A[M,K=128] @ Bt[N,128]^T.
// CLS: fp32 out (normal stores — nt stores measured 3x slower, r12) + tvec.
// ---------------------------------------------------------------------------
template<bool CLS, int NCH>
__global__ __launch_bounds__(256)
void k_mfma_gemm(const uint4* __restrict__ Au, const uint4* __restrict__ Bt,
                 void* __restrict__ Cv, const float* __restrict__ tvp,
                 int M, int N) {
    constexpr int K = HID_CH;
    constexpr int SLOTS = K / 8;       // 16
    __shared__ uint4 ldsA[64 * SLOTS];
    __shared__ uint4 ldsB[64 * SLOTS];
    const int tid = threadIdx.x;
    const int lane = tid & 63;
    const int wid = tid >> 6;
    const int wm = wid >> 1, wn = wid & 1;
    const int mbase = blockIdx.x * 64;

    for (int i = tid; i < 64 * SLOTS; i += 256) {
        int row = i / SLOTS, slot = i % SLOTS;
        int grow = mbase + row;
        uint4 val = make_uint4(0u, 0u, 0u, 0u);
        if (grow < M) val = Au[(size_t)grow * SLOTS + slot];
        ldsA[row * SLOTS + (slot ^ (row & 7))] = val;
    }
    __syncthreads();

    bf16x8 afrag[2][K / 32];
#pragma unroll
    for (int mi = 0; mi < 2; ++mi) {
        int row = wm * 32 + mi * 16 + (lane & 15);
#pragma unroll
        for (int ks = 0; ks < K / 32; ++ks) {
            int slot = ks * 4 + (lane >> 4);
            U16B u; u.u = ldsA[row * SLOTS + (slot ^ (row & 7))];
            afrag[mi][ks] = u.b;
        }
    }

#pragma unroll
    for (int chi = 0; chi < NCH; ++chi) {
        int nbase = (blockIdx.y * NCH + chi) * 64;
        __syncthreads();
        for (int i = tid; i < 64 * SLOTS; i += 256) {
            int row = i / SLOTS, slot = i % SLOTS;
            ldsB[row * SLOTS + (slot ^ (row & 7))] = Bt[(size_t)(nbase + row) * SLOTS + slot];
        }
        __syncthreads();

        f32x4 acc[2][2];
#pragma unroll
        for (int mi = 0; mi < 2; ++mi)
#pragma unroll
            for (int ni = 0; ni < 2; ++ni)
                acc[mi][ni] = f32x4{0.f, 0.f, 0.f, 0.f};

#pragma unroll
        for (int ks = 0; ks < K / 32; ++ks) {
            bf16x8 bfr[2];
#pragma unroll
            for (int ni = 0; ni < 2; ++ni) {
                int row = wn * 32 + ni * 16 + (lane & 15);
                int slot = ks * 4 + (lane >> 4);
                U16B u; u.u = ldsB[row * SLOTS + (slot ^ (row & 7))];
                bfr[ni] = u.b;
            }
#pragma unroll
            for (int mi = 0; mi < 2; ++mi)
#pragma unroll
                for (int ni = 0; ni < 2; ++ni)
                    acc[mi][ni] = __builtin_amdgcn_mfma_f32_16x16x32_bf16(
                        afrag[mi][ks], bfr[ni], acc[mi][ni], 0, 0, 0);
        }

#pragma unroll
        for (int ni = 0; ni < 2; ++ni) {
            int col = nbase + wn * 32 + ni * 16 + (lane & 15);
            float tv = 0.f;
            if (CLS && col < N) {
#pragma unroll
                for (int p = 0; p < NTVP; ++p) tv += tvp[p * OUT_CH + col];
            }
#pragma unroll
            for (int mi = 0; mi < 2; ++mi) {
                int r0 = mbase + wm * 32 + mi * 16 + (lane >> 4) * 4;
#pragma unroll
                for (int j = 0; j < 4; ++j) {
                    int r = r0 + j;
                    if (CLS) {
                        if (r < M && col < N)
                            ((float*)Cv)[(size_t)r * N + col] = acc[mi][ni][j] + tv;
                    } else {
                        if (r < M)
                            ((ushort*)Cv)[(size_t)r * N + col] = f2bf(acc[mi][ni][j]);
                    }
                }
            }
        }
    }
}

// ---------------------------------------------------------------------------
// Aggregate (bf16 H): one wave per node, lane = 2 channels (bf16x2 u32).
// div = rsqrtf(1+deg) on the fly (bit-identical to the dinv-array path).
// ---------------------------------------------------------------------------
template<bool RELU>
__global__ __launch_bounds__(256)
void k_agg(const unsigned* __restrict__ Hu, const int* __restrict__ deg,
           const int* __restrict__ bucket, const float* __restrict__ bias,
           unsigned* __restrict__ Ou) {
    int v = blockIdx.x * 4 + (threadIdx.x >> 6);
    if (v >= N_NODES) return;
    int lane = threadIdx.x & 63;
    int dgv = deg[v];
    float di = rsqrtf(1.0f + (float)dgv);
    unsigned h = Hu[(size_t)v * 64 + lane];
    float a0 = bf2f(h & 0xffffu) * di;
    float a1 = bf2f(h >> 16) * di;
    int dg = dgv > MAX_DEG ? MAX_DEG : dgv;
    const int4* brow = (const int4*)(bucket + (v << 6));
    int j = 0;
    for (; j + 4 <= dg; j += 4) {
        int4 s4 = brow[j >> 2];
        float d0 = rsqrtf(1.0f + (float)deg[s4.x]);
        float d1 = rsqrtf(1.0f + (float)deg[s4.y]);
        float d2 = rsqrtf(1.0f + (float)deg[s4.z]);
        float d3 = rsqrtf(1.0f + (float)deg[s4.w]);
        unsigned q0 = Hu[(size_t)s4.x * 64 + lane];
        unsigned q1 = Hu[(size_t)s4.y * 64 + lane];
        unsigned q2 = Hu[(size_t)s4.z * 64 + lane];
        unsigned q3 = Hu[(size_t)s4.w * 64 + lane];
        a0 += bf2f(q0 & 0xffffu) * d0 + bf2f(q1 & 0xffffu) * d1
            + bf2f(q2 & 0xffffu) * d2 + bf2f(q3 & 0xffffu) * d3;
        a1 += bf2f(q0 >> 16) * d0 + bf2f(q1 >> 16) * d1
            + bf2f(q2 >> 16) * d2 + bf2f(q3 >> 16) * d3;
    }
    for (; j < dg; ++j) {
        int s = bucket[(v << 6) + j];
        float ds = rsqrtf(1.0f + (float)deg[s]);
        unsigned q = Hu[(size_t)s * 64 + lane];
        a0 += bf2f(q & 0xffffu) * ds;
        a1 += bf2f(q >> 16) * ds;
    }
    a0 = a0 * di + bias[lane * 2];
    a1 = a1 * di + bias[lane * 2 + 1];
    if (RELU) { a0 = fmaxf(a0, 0.f); a1 = fmaxf(a1, 0.f); }
    Ou[(size_t)v * 64 + lane] = (unsigned)f2bf(a0) | ((unsigned)f2bf(a1) << 16);
}

// ---------------------------------------------------------------------------
extern "C" void kernel_launch(void* const* d_in, const int* in_sizes, int n_in,
                              void* d_out, int out_size, void* d_ws, size_t ws_size,
                              hipStream_t stream) {
    const float* x    = (const float*)d_in[0];
    const int*   ei   = (const int*)d_in[1];
    const float* text = (const float*)d_in[2];
    const float* W1   = (const float*)d_in[3];
    const float* b1   = (const float*)d_in[4];
    const float* W2   = (const float*)d_in[5];
    const float* b2   = (const float*)d_in[6];
    const float* Wc   = (const float*)d_in[7];
    const float* bc   = (const float*)d_in[8];
    float* out = (float*)d_out;

    const int* e_src = ei;
    const int* e_dst = ei + N_EDGES;

    char* ws = (char*)d_ws;
    size_t off = 0;
    auto alloc = [&](size_t bytes) {
        size_t o = off;
        off += (bytes + 255) & ~(size_t)255;
        return o;
    };
    ushort* G0      = (ushort*)(ws + alloc((size_t)N_NODES * HID_CH * 2));
    ushort* G1      = (ushort*)(ws + alloc((size_t)N_NODES * HID_CH * 2));
    int*    pos     = (int*)   (ws + alloc((size_t)N_NODES * 4));
    int*    bucket  = (int*)   (ws + alloc((size_t)N_NODES * MAX_DEG * 4));
    float*  tvp     = (float*) (ws + alloc((size_t)NTVP * OUT_CH * 4));
    ushort* Wt1     = (ushort*)(ws + alloc((size_t)HID_CH * IN_CH * 2));
    ushort* Wt2     = (ushort*)(ws + alloc((size_t)HID_CH * HID_CH * 2));
    ushort* Wct     = (ushort*)(ws + alloc((size_t)1024 * HID_CH * 2));
    (void)ws_size; (void)in_sizes; (void)n_in; (void)out_size;

    // --- prep: transposes + tvec partials + pos zero (1 dispatch) ---
    k_prep<<<141, 256, 0, stream>>>(W1, W2, Wc, bc, text, Wt1, Wt2, Wct, tvp,
                                    (int4*)pos);

    // --- fused: G0 = x @ W1  ||  bucket fill (1 dispatch) ---
    k_gemm1_fill<<<MTILES + NB_FILL, 256, 0, stream>>>(
        x, (const uint4*)Wt1, G0, e_src, e_dst, pos, bucket);

    // --- agg1: G1 = relu(Agg(G0) + b1) ---
    k_agg<true><<<(N_NODES + 3) / 4, 256, 0, stream>>>(
        (const unsigned*)G0, pos, bucket, b1, (unsigned*)G1);

    // --- layer 2 GEMM: G0 = G1 @ W2 ---
    k_mfma_gemm<false, 1><<<dim3(MTILES, 2), 256, 0, stream>>>(
        (const uint4*)G1, (const uint4*)Wt2, G0, nullptr, N_NODES, HID_CH);

    // --- agg2: G1 = Agg(G0) + b2 ---
    k_agg<false><<<(N_NODES + 3) / 4, 256, 0, stream>>>(
        (const unsigned*)G0, pos, bucket, b2, (unsigned*)G1);

    // --- classifier: out = G1 @ Wct^T + sum(tvp) ; grid (782, 8), NCH=2 ---
    k_mfma_gemm<true, 2><<<dim3(MTILES, 8), 256, 0, stream>>>(
        (const uint4*)G1, (const uint4*)Wct, out, tvp, N_NODES, OUT_CH);
}